// Round 7
// baseline (433.813 us; speedup 1.0000x reference)
//
#include <hip/hip_runtime.h>
#include <hip/hip_bf16.h>
#include <math.h>

#define B_    2
#define T_    2048
#define CEMB  2048
#define NH    16
#define NKV   4
#define DHD   128
#define QKVD  3072   // CEMB + 2*NKV*DHD

typedef unsigned short u16;
typedef unsigned int   u32;
typedef __attribute__((ext_vector_type(8))) short  short8;   // 8 bf16 = 4 VGPRs
typedef __attribute__((ext_vector_type(4))) float  floatx4;  // MFMA accumulator

static __device__ __forceinline__ u16 f2bf(float f){
    union{float f;u32 u;}x; x.f = f; u32 u = x.u;
    return (u16)((u + 0x7fffu + ((u >> 16) & 1u)) >> 16);
}
static __device__ __forceinline__ float lo2f(u32 w){ union{u32 u;float f;}x; x.u = w << 16; return x.f; }
static __device__ __forceinline__ float hi2f(u32 w){ union{u32 u;float f;}x; x.u = w & 0xffff0000u; return x.f; }

// Async global->LDS 16B copy: LDS dest is wave-uniform base + lane*16.
static __device__ __forceinline__ void async_cp16(const u16* g, u16* lds_wave_base) {
    __builtin_amdgcn_global_load_lds(
        (const __attribute__((address_space(1))) void*)g,
        (__attribute__((address_space(3))) void*)lds_wave_base, 16, 0, 0);
}

// ---------------------------------------------------------------------------
// f32 -> bf16 convert (no transpose), 8 elements/thread.
// ---------------------------------------------------------------------------
__global__ __launch_bounds__(256) void convert_kernel(const float* __restrict__ in,
                                                      u16* __restrict__ out, int n8)
{
    const int i = blockIdx.x * 256 + threadIdx.x;
    if (i >= n8) return;
    const float4* p = reinterpret_cast<const float4*>(in);
    float4 a = p[i * 2], b = p[i * 2 + 1];
    uint4 o;
    o.x = (u32)f2bf(a.x) | ((u32)f2bf(a.y) << 16);
    o.y = (u32)f2bf(a.z) | ((u32)f2bf(a.w) << 16);
    o.z = (u32)f2bf(b.x) | ((u32)f2bf(b.y) << 16);
    o.w = (u32)f2bf(b.z) | ((u32)f2bf(b.w) << 16);
    reinterpret_cast<uint4*>(out)[i] = o;
}

// ---------------------------------------------------------------------------
// f32 [R][Cn] -> bf16 [Cn][R] (transpose + convert). 32x32 tiles.
// ---------------------------------------------------------------------------
__global__ __launch_bounds__(256) void transpose_f32_bf16(const float* __restrict__ in,
                                                          u16* __restrict__ out,
                                                          int R, int Cn)
{
    __shared__ float tl[32][33];
    const int tx = threadIdx.x & 31, ty = threadIdx.x >> 5;
    const int c0 = blockIdx.x << 5, r0 = blockIdx.y << 5;
    #pragma unroll
    for (int i = 0; i < 4; ++i)
        tl[ty + i * 8][tx] = in[(size_t)(r0 + ty + i * 8) * Cn + c0 + tx];
    __syncthreads();
    #pragma unroll
    for (int i = 0; i < 4; ++i)
        out[(size_t)(c0 + ty + i * 8) * R + r0 + tx] = f2bf(tl[tx][ty + i * 8]);
}

// ---------------------------------------------------------------------------
// Build V^T: vt[(b*NKV+kv)*DHD + d][T_] = qkv[b*T_+t][2560 + kv*128 + d]
// ---------------------------------------------------------------------------
__global__ __launch_bounds__(256) void vt_build_kernel(const u16* __restrict__ qkv,
                                                       u16* __restrict__ vt)
{
    __shared__ u16 tl[32][33];
    const int tx = threadIdx.x & 31, ty = threadIdx.x >> 5;
    const int t0 = blockIdx.x << 5, d0 = blockIdx.y << 5;
    const int b = blockIdx.z >> 2, kv = blockIdx.z & 3;
    #pragma unroll
    for (int i = 0; i < 4; ++i)
        tl[ty + i * 8][tx] =
            qkv[(size_t)(b * T_ + t0 + ty + i * 8) * QKVD + CEMB + NKV * DHD + kv * DHD + d0 + tx];
    __syncthreads();
    #pragma unroll
    for (int i = 0; i < 4; ++i)
        vt[(size_t)((b * NKV + kv) * DHD + d0 + ty + i * 8) * T_ + t0 + tx] = tl[tx][ty + i * 8];
}

// ---------------------------------------------------------------------------
// MFMA GEMM: C[M,N] = A[M,K] @ B[K,N] with BT = B^T ([N][K] row-major).
// 128x128 tile, BK=32, 256 thr = 4 waves in 2x2, global_load_lds staging.
// ---------------------------------------------------------------------------
template <bool F32OUT>
__global__ __launch_bounds__(256) void gemm_mfma_kernel(const u16* __restrict__ A,
                                                        const u16* __restrict__ BT,
                                                        void* __restrict__ Cv,
                                                        int M, int N, int K)
{
    __shared__ u16 As[128 * 32];
    __shared__ u16 Bs[128 * 32];
    const int tid  = threadIdx.x;
    const int lane = tid & 63;
    const int wv   = tid >> 6;
    const int n16  = lane & 15;
    const int quad = lane >> 4;
    const int wm   = wv >> 1, wn = wv & 1;
    const int row0 = blockIdx.y << 7;
    const int col0 = blockIdx.x << 7;

    floatx4 acc[4][4];
    #pragma unroll
    for (int i = 0; i < 4; ++i)
        #pragma unroll
        for (int j = 0; j < 4; ++j) acc[i][j] = (floatx4)0.0f;

    for (int k0 = 0; k0 < K; k0 += 32) {
        __syncthreads();
        #pragma unroll
        for (int it = 0; it < 2; ++it) {
            const int idx = it * 256 + tid;      // 0..511
            const int m = idx >> 2, k8 = (idx & 3) << 3;
            async_cp16(A  + (size_t)(row0 + m) * K + k0 + k8, &As[(it * 256 + wv * 64) * 8]);
            async_cp16(BT + (size_t)(col0 + m) * K + k0 + k8, &Bs[(it * 256 + wv * 64) * 8]);
        }
        __syncthreads();
        short8 af[4], bf[4];
        #pragma unroll
        for (int mt = 0; mt < 4; ++mt)
            af[mt] = *reinterpret_cast<const short8*>(&As[(wm * 64 + mt * 16 + n16) * 32 + quad * 8]);
        #pragma unroll
        for (int nt = 0; nt < 4; ++nt)
            bf[nt] = *reinterpret_cast<const short8*>(&Bs[(wn * 64 + nt * 16 + n16) * 32 + quad * 8]);
        #pragma unroll
        for (int mt = 0; mt < 4; ++mt)
            #pragma unroll
            for (int nt = 0; nt < 4; ++nt)
                acc[mt][nt] = __builtin_amdgcn_mfma_f32_16x16x32_bf16(af[mt], bf[nt], acc[mt][nt], 0, 0, 0);
    }
    #pragma unroll
    for (int mt = 0; mt < 4; ++mt) {
        #pragma unroll
        for (int r = 0; r < 4; ++r) {
            const int row = row0 + wm * 64 + mt * 16 + quad * 4 + r;
            if (F32OUT) {
                float* C = reinterpret_cast<float*>(Cv);
                #pragma unroll
                for (int nt = 0; nt < 4; ++nt)
                    C[(size_t)row * N + col0 + wn * 64 + nt * 16 + n16] = acc[mt][nt][r];
            } else {
                u16* C = reinterpret_cast<u16*>(Cv);
                #pragma unroll
                for (int nt = 0; nt < 4; ++nt)
                    C[(size_t)row * N + col0 + wn * 64 + nt * 16 + n16] = f2bf(acc[mt][nt][r]);
            }
        }
    }
}

// ---------------------------------------------------------------------------
// RoPE / YaRN in-place on q (16 heads) + k (4 heads) of qkv (bf16).
// ---------------------------------------------------------------------------
__global__ __launch_bounds__(256) void rope_kernel(
    u16* __restrict__ qkv, const float attn_factor, const float low, const float high)
{
    const int total = B_ * T_ * (NH + NKV) * (DHD / 2);
    int idx = blockIdx.x * 256 + threadIdx.x;
    if (idx >= total) return;
    const int d = idx & 63;
    int r = idx >> 6;
    const int h = r % (NH + NKV);
    r /= (NH + NKV);
    const int t = r % T_;
    const int b = r / T_;
    const int off = (h < NH) ? (h * DHD) : (CEMB + (h - NH) * DHD);

    u32* p = reinterpret_cast<u32*>(qkv + (size_t)(b * T_ + t) * QKVD + off) + d;
    u32 w = *p;
    float xe = lo2f(w), xo = hi2f(w);

    float df   = (float)d;
    float ramp = (df - low) / (high - low);
    ramp = fminf(fmaxf(ramp, 0.0f), 1.0f);
    float pf     = expf((2.0f * df / 128.0f) * 13.815510557964274f); // base^(2d/dim)
    float inv_ex = 1.0f / pf;
    float inv    = inv_ex * ((1.0f / 64.0f) * ramp + (1.0f - ramp));
    float ang = (float)t * inv;
    float s = sinf(ang), c = cosf(ang);
    float oe = (xe * c - xo * s) * attn_factor;
    float oo = (xe * s + xo * c) * attn_factor;
    *p = (u32)f2bf(oe) | ((u32)f2bf(oo) << 16);
}

// ---------------------------------------------------------------------------
// MFMA flash attention (causal, GQA). Block = 256 thr (4 waves).
// R7: __launch_bounds__(256, 2) — grid is exactly 2 blocks/CU, so request
// 2 waves/EU. This raises the VGPR cap to ~256 so the 32 prefetch registers
// (kr/vr) allocate instead of spilling to scratch (R6: ~360 MB HBM scratch
// writes at VGPR cap 104). Structure/math identical to R6.
// ---------------------------------------------------------------------------
__global__ __launch_bounds__(256, 2) void attn_mfma_kernel(const u16* __restrict__ qkv,
                                                           const u16* __restrict__ vt,
                                                           u16* __restrict__ y)
{
    __shared__ u16 Ks[64 * 136];     // K tile [key][d], row stride 136
    __shared__ u16 Vts[128 * 72];    // V^T tile [d][key], row stride 72
    __shared__ u16 Pl[4 * 16 * 72];  // per-wave P [q][key], row stride 72

    const int tid  = threadIdx.x;
    const int lane = tid & 63;
    const int wv   = tid >> 6;
    const int n16  = lane & 15;
    const int quad = lane >> 4;
    const int nx   = blockIdx.x;     // 0..15
    const int bh   = blockIdx.y;
    const int b    = bh >> 4;
    const int h    = bh & 15;
    const int kh   = h >> 2;

    const float C1 = 0.08838834764831845f * 1.4426950408889634f;  // scale * log2(e)

    u16* plw = Pl + wv * 16 * 72;
    const u16* kbase = qkv + (size_t)(b * T_) * QKVD + CEMB + kh * DHD;
    const u16* vbase = vt + (size_t)((b * NKV + kh) * DHD) * T_;

    #pragma unroll
    for (int qt = 0; qt < 2; ++qt) {
        const int i0 = ((qt == 0) ? (31 - nx) : nx) << 6;   // heavy tile first

        // Q fragments (B-operand of S^T = K*Q^T): lane's query = i0 + wv*16 + n16
        const int qrow = i0 + wv * 16 + n16;
        const u16* qp = qkv + (size_t)(b * T_ + qrow) * QKVD + h * DHD;
        short8 qf[4];
        #pragma unroll
        for (int kk = 0; kk < 4; ++kk)
            qf[kk] = *reinterpret_cast<const short8*>(qp + kk * 32 + quad * 8);

        floatx4 oacc[8];
        #pragma unroll
        for (int i = 0; i < 8; ++i) oacc[i] = (floatx4)0.0f;
        float m_cur = -INFINITY, l_cur = 0.0f;

        // initial prefetch (tile j0 = 0)
        uint4 kr[4], vr[4];
        #pragma unroll
        for (int it = 0; it < 4; ++it) {
            const int idx = it * 256 + tid;
            kr[it] = *reinterpret_cast<const uint4*>(
                kbase + (size_t)(idx >> 4) * QKVD + ((idx & 15) << 3));
            vr[it] = *reinterpret_cast<const uint4*>(
                vbase + (size_t)(idx >> 3) * T_ + ((idx & 7) << 3));
        }

        for (int j0 = 0; j0 <= i0; j0 += 64) {
            __syncthreads();   // all waves done reading Ks/Vts of previous tile
            #pragma unroll
            for (int it = 0; it < 4; ++it) {
                const int idx = it * 256 + tid;
                *reinterpret_cast<uint4*>(&Ks[(idx >> 4) * 136 + ((idx & 15) << 3)]) = kr[it];
                *reinterpret_cast<uint4*>(&Vts[(idx >> 3) * 72 + ((idx & 7) << 3)]) = vr[it];
            }
            if (j0 + 64 <= i0) {   // prefetch next tile; latency hides under compute
                const int jn = j0 + 64;
                #pragma unroll
                for (int it = 0; it < 4; ++it) {
                    const int idx = it * 256 + tid;
                    kr[it] = *reinterpret_cast<const uint4*>(
                        kbase + (size_t)(jn + (idx >> 4)) * QKVD + ((idx & 15) << 3));
                    vr[it] = *reinterpret_cast<const uint4*>(
                        vbase + (size_t)(idx >> 3) * T_ + jn + ((idx & 7) << 3));
                }
            }
            __syncthreads();

            // ---- S^T = K * Q^T : st[t] covers keys [j0+t*16, j0+t*16+16)
            floatx4 st[4];
            #pragma unroll
            for (int t = 0; t < 4; ++t) st[t] = (floatx4)0.0f;
            #pragma unroll
            for (int t = 0; t < 4; ++t) {
                #pragma unroll
                for (int kk = 0; kk < 4; ++kk) {
                    short8 a = *reinterpret_cast<const short8*>(
                        &Ks[(t * 16 + n16) * 136 + kk * 32 + quad * 8]);
                    st[t] = __builtin_amdgcn_mfma_f32_16x16x32_bf16(a, qf[kk], st[t], 0, 0, 0);
                }
            }

            // ---- causal mask + per-lane online softmax (lane's query = qrow)
            const bool diag = (j0 + 63 > i0 + wv * 16);
            float mloc = m_cur;
            #pragma unroll
            for (int t = 0; t < 4; ++t) {
                #pragma unroll
                for (int r = 0; r < 4; ++r) {
                    float s = st[t][r];
                    if (diag) {
                        const int key = j0 + t * 16 + quad * 4 + r;
                        if (key > qrow) s = -INFINITY;
                    }
                    st[t][r] = s;
                    mloc = fmaxf(mloc, s);
                }
            }
            mloc = fmaxf(mloc, __shfl_xor(mloc, 16));
            mloc = fmaxf(mloc, __shfl_xor(mloc, 32));
            const float alpha = exp2f((m_cur - mloc) * C1);
            m_cur = mloc;

            float lsum = 0.0f;
            #pragma unroll
            for (int t = 0; t < 4; ++t) {
                float p0 = exp2f((st[t][0] - mloc) * C1);
                float p1 = exp2f((st[t][1] - mloc) * C1);
                float p2 = exp2f((st[t][2] - mloc) * C1);
                float p3 = exp2f((st[t][3] - mloc) * C1);
                lsum += (p0 + p1) + (p2 + p3);
                uint2 pk;
                pk.x = (u32)f2bf(p0) | ((u32)f2bf(p1) << 16);
                pk.y = (u32)f2bf(p2) | ((u32)f2bf(p3) << 16);
                *reinterpret_cast<uint2*>(&plw[n16 * 72 + t * 16 + quad * 4]) = pk;
            }
            lsum += __shfl_xor(lsum, 16);
            lsum += __shfl_xor(lsum, 32);
            l_cur = l_cur * alpha + lsum;

            #pragma unroll
            for (int dt = 0; dt < 8; ++dt) {
                oacc[dt][0] *= alpha; oacc[dt][1] *= alpha;
                oacc[dt][2] *= alpha; oacc[dt][3] *= alpha;
            }

            // ---- O^T += V^T * P^T  (wave-private Pl; same-wave LDS in-order)
            #pragma unroll
            for (int kt = 0; kt < 2; ++kt) {
                short8 pfrag = *reinterpret_cast<const short8*>(&plw[n16 * 72 + kt * 32 + quad * 8]);
                #pragma unroll
                for (int dt = 0; dt < 8; ++dt) {
                    short8 vfrag = *reinterpret_cast<const short8*>(
                        &Vts[(dt * 16 + n16) * 72 + kt * 32 + quad * 8]);
                    oacc[dt] = __builtin_amdgcn_mfma_f32_16x16x32_bf16(vfrag, pfrag, oacc[dt], 0, 0, 0);
                }
            }
        }

        // ---- epilogue: O^T[d][q] regs -> y[qrow][h*128 + d], d = dt*16+quad*4+r
        const float linv = 1.0f / l_cur;
        u16* yp = y + (size_t)(b * T_ + qrow) * CEMB + h * DHD + quad * 4;
        #pragma unroll
        for (int dt = 0; dt < 8; ++dt) {
            u32 w0 = (u32)f2bf(oacc[dt][0] * linv) | ((u32)f2bf(oacc[dt][1] * linv) << 16);
            u32 w1 = (u32)f2bf(oacc[dt][2] * linv) | ((u32)f2bf(oacc[dt][3] * linv) << 16);
            *reinterpret_cast<u32*>(yp + dt * 16)     = w0;
            *reinterpret_cast<u32*>(yp + dt * 16 + 2) = w1;
        }
    }
}

// ---------------------------------------------------------------------------
extern "C" void kernel_launch(void* const* d_in, const int* in_sizes, int n_in,
                              void* d_out, int out_size, void* d_ws, size_t ws_size,
                              hipStream_t stream) {
    const size_t NX   = (size_t)B_ * T_ * CEMB;     // 8,388,608
    const size_t NWQ  = (size_t)CEMB * QKVD;        // 6,291,456
    const size_t NWO  = (size_t)CEMB * CEMB;        // 4,194,304
    const size_t NQKV = (size_t)B_ * T_ * QKVD;     // 12,582,912
    const size_t NY   = NX;

    u16* qkv = (u16*)d_ws;
    u16* y   = qkv + NQKV;
    u16* xb  = y + NY;
    u16* wqT = xb + NX;
    u16* woT = wqT + NWQ;
    u16* vtb = xb;   // alias: xb dead after GEMM1; Vt needs 2.1M u16 <= 8.4M

    // --- input conversion (f32 -> bf16), weights transposed for BT GEMM
    convert_kernel<<<(int)(NX / 8 + 255) / 256, 256, 0, stream>>>((const float*)d_in[0], xb, (int)(NX / 8));
    transpose_f32_bf16<<<dim3(QKVD / 32, CEMB / 32), 256, 0, stream>>>((const float*)d_in[1], wqT, CEMB, QKVD);
    transpose_f32_bf16<<<dim3(CEMB / 32, CEMB / 32), 256, 0, stream>>>((const float*)d_in[2], woT, CEMB, CEMB);

    // --- GEMM1: qkv = x @ w_qkv (bf16 out)
    gemm_mfma_kernel<false><<<dim3(QKVD / 128, (B_ * T_) / 128), 256, 0, stream>>>(
        xb, wqT, qkv, B_ * T_, QKVD, CEMB);

    // --- RoPE constants (host, double precision, mirrors numpy)
    const double two_pi = 6.283185307179586476925286766559;
    double corr4 = 128.0 * log(4096.0 / (4.0 * two_pi)) / (2.0 * log(1.0e6));
    double corr1 = 128.0 * log(4096.0 / (1.0 * two_pi)) / (2.0 * log(1.0e6));
    double lowd  = floor(corr4); if (lowd < 0.0) lowd = 0.0;
    double highd = ceil(corr1);  if (highd > 127.0) highd = 127.0;
    if (lowd == highd) highd += 0.001;
    float attn_factor = (float)(0.1 * log(64.0) + 1.0);

    const int rope_total = B_ * T_ * (NH + NKV) * (DHD / 2);
    rope_kernel<<<(rope_total + 255) / 256, 256, 0, stream>>>(
        qkv, attn_factor, (float)lowd, (float)highd);

    // --- V^T buffer (overwrites xb, which is no longer needed)
    vt_build_kernel<<<dim3(T_ / 32, DHD / 32, B_ * NKV), 256, 0, stream>>>(qkv, vtb);

    // --- flash attention -> y (bf16); balanced pairing grid (16, 32)
    attn_mfma_kernel<<<dim3(T_ / 128, B_ * NH), 256, 0, stream>>>(qkv, vtb, y);

    // --- GEMM2: out = y @ w_o (f32 out)
    gemm_mfma_kernel<true><<<dim3(CEMB / 128, (B_ * T_) / 128), 256, 0, stream>>>(
        y, woT, d_out, B_ * T_, CEMB, CEMB);
}

// Round 8
// 338.078 us; speedup vs baseline: 1.2832x; 1.2832x over previous
//
#include <hip/hip_runtime.h>
#include <hip/hip_bf16.h>
#include <math.h>

#define B_    2
#define T_    2048
#define CEMB  2048
#define NH    16
#define NKV   4
#define DHD   128
#define QKVD  3072   // CEMB + 2*NKV*DHD

typedef unsigned short u16;
typedef unsigned int   u32;
typedef __attribute__((ext_vector_type(8))) short  short8;   // 8 bf16 = 4 VGPRs
typedef __attribute__((ext_vector_type(4))) float  floatx4;  // MFMA accumulator

static __device__ __forceinline__ u16 f2bf(float f){
    union{float f;u32 u;}x; x.f = f; u32 u = x.u;
    return (u16)((u + 0x7fffu + ((u >> 16) & 1u)) >> 16);
}
static __device__ __forceinline__ float lo2f(u32 w){ union{u32 u;float f;}x; x.u = w << 16; return x.f; }
static __device__ __forceinline__ float hi2f(u32 w){ union{u32 u;float f;}x; x.u = w & 0xffff0000u; return x.f; }

// Async global->LDS 16B copy: LDS dest is wave-uniform base + lane*16.
static __device__ __forceinline__ void async_cp16(const u16* g, u16* lds_wave_base) {
    __builtin_amdgcn_global_load_lds(
        (const __attribute__((address_space(1))) void*)g,
        (__attribute__((address_space(3))) void*)lds_wave_base, 16, 0, 0);
}

// ---------------------------------------------------------------------------
// f32 -> bf16 convert (no transpose), 8 elements/thread.
// ---------------------------------------------------------------------------
__global__ __launch_bounds__(256) void convert_kernel(const float* __restrict__ in,
                                                      u16* __restrict__ out, int n8)
{
    const int i = blockIdx.x * 256 + threadIdx.x;
    if (i >= n8) return;
    const float4* p = reinterpret_cast<const float4*>(in);
    float4 a = p[i * 2], b = p[i * 2 + 1];
    uint4 o;
    o.x = (u32)f2bf(a.x) | ((u32)f2bf(a.y) << 16);
    o.y = (u32)f2bf(a.z) | ((u32)f2bf(a.w) << 16);
    o.z = (u32)f2bf(b.x) | ((u32)f2bf(b.y) << 16);
    o.w = (u32)f2bf(b.z) | ((u32)f2bf(b.w) << 16);
    reinterpret_cast<uint4*>(out)[i] = o;
}

// ---------------------------------------------------------------------------
// f32 [R][Cn] -> bf16 [Cn][R] (transpose + convert). 32x32 tiles.
// ---------------------------------------------------------------------------
__global__ __launch_bounds__(256) void transpose_f32_bf16(const float* __restrict__ in,
                                                          u16* __restrict__ out,
                                                          int R, int Cn)
{
    __shared__ float tl[32][33];
    const int tx = threadIdx.x & 31, ty = threadIdx.x >> 5;
    const int c0 = blockIdx.x << 5, r0 = blockIdx.y << 5;
    #pragma unroll
    for (int i = 0; i < 4; ++i)
        tl[ty + i * 8][tx] = in[(size_t)(r0 + ty + i * 8) * Cn + c0 + tx];
    __syncthreads();
    #pragma unroll
    for (int i = 0; i < 4; ++i)
        out[(size_t)(c0 + ty + i * 8) * R + r0 + tx] = f2bf(tl[tx][ty + i * 8]);
}

// ---------------------------------------------------------------------------
// Build V^T: vt[(b*NKV+kv)*DHD + d][T_] = qkv[b*T_+t][2560 + kv*128 + d]
// ---------------------------------------------------------------------------
__global__ __launch_bounds__(256) void vt_build_kernel(const u16* __restrict__ qkv,
                                                       u16* __restrict__ vt)
{
    __shared__ u16 tl[32][33];
    const int tx = threadIdx.x & 31, ty = threadIdx.x >> 5;
    const int t0 = blockIdx.x << 5, d0 = blockIdx.y << 5;
    const int b = blockIdx.z >> 2, kv = blockIdx.z & 3;
    #pragma unroll
    for (int i = 0; i < 4; ++i)
        tl[ty + i * 8][tx] =
            qkv[(size_t)(b * T_ + t0 + ty + i * 8) * QKVD + CEMB + NKV * DHD + kv * DHD + d0 + tx];
    __syncthreads();
    #pragma unroll
    for (int i = 0; i < 4; ++i)
        vt[(size_t)((b * NKV + kv) * DHD + d0 + ty + i * 8) * T_ + t0 + tx] = tl[tx][ty + i * 8];
}

// ---------------------------------------------------------------------------
// MFMA GEMM: C[M,N] = A[M,K] @ B[K,N] with BT = B^T ([N][K] row-major).
// 128x128 tile, BK=32, 256 thr = 4 waves in 2x2, global_load_lds staging.
// (unchanged from R6/R7 — known good)
// ---------------------------------------------------------------------------
template <bool F32OUT>
__global__ __launch_bounds__(256) void gemm_mfma_kernel(const u16* __restrict__ A,
                                                        const u16* __restrict__ BT,
                                                        void* __restrict__ Cv,
                                                        int M, int N, int K)
{
    __shared__ u16 As[128 * 32];
    __shared__ u16 Bs[128 * 32];
    const int tid  = threadIdx.x;
    const int lane = tid & 63;
    const int wv   = tid >> 6;
    const int n16  = lane & 15;
    const int quad = lane >> 4;
    const int wm   = wv >> 1, wn = wv & 1;
    const int row0 = blockIdx.y << 7;
    const int col0 = blockIdx.x << 7;

    floatx4 acc[4][4];
    #pragma unroll
    for (int i = 0; i < 4; ++i)
        #pragma unroll
        for (int j = 0; j < 4; ++j) acc[i][j] = (floatx4)0.0f;

    for (int k0 = 0; k0 < K; k0 += 32) {
        __syncthreads();
        #pragma unroll
        for (int it = 0; it < 2; ++it) {
            const int idx = it * 256 + tid;      // 0..511
            const int m = idx >> 2, k8 = (idx & 3) << 3;
            async_cp16(A  + (size_t)(row0 + m) * K + k0 + k8, &As[(it * 256 + wv * 64) * 8]);
            async_cp16(BT + (size_t)(col0 + m) * K + k0 + k8, &Bs[(it * 256 + wv * 64) * 8]);
        }
        __syncthreads();
        short8 af[4], bf[4];
        #pragma unroll
        for (int mt = 0; mt < 4; ++mt)
            af[mt] = *reinterpret_cast<const short8*>(&As[(wm * 64 + mt * 16 + n16) * 32 + quad * 8]);
        #pragma unroll
        for (int nt = 0; nt < 4; ++nt)
            bf[nt] = *reinterpret_cast<const short8*>(&Bs[(wn * 64 + nt * 16 + n16) * 32 + quad * 8]);
        #pragma unroll
        for (int mt = 0; mt < 4; ++mt)
            #pragma unroll
            for (int nt = 0; nt < 4; ++nt)
                acc[mt][nt] = __builtin_amdgcn_mfma_f32_16x16x32_bf16(af[mt], bf[nt], acc[mt][nt], 0, 0, 0);
    }
    #pragma unroll
    for (int mt = 0; mt < 4; ++mt) {
        #pragma unroll
        for (int r = 0; r < 4; ++r) {
            const int row = row0 + wm * 64 + mt * 16 + quad * 4 + r;
            if (F32OUT) {
                float* C = reinterpret_cast<float*>(Cv);
                #pragma unroll
                for (int nt = 0; nt < 4; ++nt)
                    C[(size_t)row * N + col0 + wn * 64 + nt * 16 + n16] = acc[mt][nt][r];
            } else {
                u16* C = reinterpret_cast<u16*>(Cv);
                #pragma unroll
                for (int nt = 0; nt < 4; ++nt)
                    C[(size_t)row * N + col0 + wn * 64 + nt * 16 + n16] = f2bf(acc[mt][nt][r]);
            }
        }
    }
}

// ---------------------------------------------------------------------------
// RoPE / YaRN in-place on q (16 heads) + k (4 heads) of qkv (bf16).
// ---------------------------------------------------------------------------
__global__ __launch_bounds__(256) void rope_kernel(
    u16* __restrict__ qkv, const float attn_factor, const float low, const float high)
{
    const int total = B_ * T_ * (NH + NKV) * (DHD / 2);
    int idx = blockIdx.x * 256 + threadIdx.x;
    if (idx >= total) return;
    const int d = idx & 63;
    int r = idx >> 6;
    const int h = r % (NH + NKV);
    r /= (NH + NKV);
    const int t = r % T_;
    const int b = r / T_;
    const int off = (h < NH) ? (h * DHD) : (CEMB + (h - NH) * DHD);

    u32* p = reinterpret_cast<u32*>(qkv + (size_t)(b * T_ + t) * QKVD + off) + d;
    u32 w = *p;
    float xe = lo2f(w), xo = hi2f(w);

    float df   = (float)d;
    float ramp = (df - low) / (high - low);
    ramp = fminf(fmaxf(ramp, 0.0f), 1.0f);
    float pf     = expf((2.0f * df / 128.0f) * 13.815510557964274f); // base^(2d/dim)
    float inv_ex = 1.0f / pf;
    float inv    = inv_ex * ((1.0f / 64.0f) * ramp + (1.0f - ramp));
    float ang = (float)t * inv;
    float s = sinf(ang), c = cosf(ang);
    float oe = (xe * c - xo * s) * attn_factor;
    float oo = (xe * s + xo * c) * attn_factor;
    *p = (u32)f2bf(oe) | ((u32)f2bf(oo) << 16);
}

// ---------------------------------------------------------------------------
// MFMA flash attention (causal, GQA). Block = 256 thr (4 waves).
// R8: async global_load_lds DOUBLE-BUFFER pipeline — no prefetch registers
// (R6/R7's register prefetch was scratch-spilled by the compiler: ~310 MB
// HBM writes). One barrier per key-tile; DMA for tile j+1 issues right after
// it and drains at the NEXT barrier (a full compute section later).
// LDS layout is unpadded (DMA requires contiguous lane-order dest); bank
// conflicts avoided by XOR chunk swizzle applied to the GLOBAL source addr:
//   Ks:  physical chunk pc = lc ^ (row & 15)   (row=key, 16 chunks/row)
//   Vts: physical chunk pc = lc ^ (row & 7)    (row=d,    8 chunks/row)
// Fragment reads invert the same swizzle -> 8 dwords/bank (minimum).
// Math identical to the verified R5 kernel.
// ---------------------------------------------------------------------------
__global__ __launch_bounds__(256, 2) void attn_mfma_kernel(const u16* __restrict__ qkv,
                                                           const u16* __restrict__ vt,
                                                           u16* __restrict__ y)
{
    __shared__ __align__(16) u16 Ksd[2][64 * 128];   // [buf][key][d]  (swizzled chunks)
    __shared__ __align__(16) u16 Vtsd[2][128 * 64];  // [buf][d][key]  (swizzled chunks)
    __shared__ u16 Pl[4 * 16 * 72];                  // per-wave P [q][key], stride 72

    const int tid  = threadIdx.x;
    const int lane = tid & 63;
    const int wv   = tid >> 6;
    const int n16  = lane & 15;
    const int quad = lane >> 4;
    const int nx   = blockIdx.x;     // 0..15
    const int bh   = blockIdx.y;
    const int b    = bh >> 4;
    const int h    = bh & 15;
    const int kh   = h >> 2;

    const float C1 = 0.08838834764831845f * 1.4426950408889634f;  // scale * log2(e)

    u16* plw = Pl + wv * 16 * 72;
    const u16* kbase = qkv + (size_t)(b * T_) * QKVD + CEMB + kh * DHD;
    const u16* vbase = vt + (size_t)((b * NKV + kh) * DHD) * T_;

    // DMA one 64-key K tile (16 KB) into Ksd[buf] with XOR-chunk swizzle.
    auto dma_k = [&](int j0, int buf) {
        #pragma unroll
        for (int it = 0; it < 4; ++it) {
            const int P   = it * 256 + tid;          // physical chunk 0..1023
            const int row = P >> 4;                  // key 0..63
            const int lc  = (P & 15) ^ (row & 15);   // logical chunk (d/8)
            async_cp16(kbase + (size_t)(j0 + row) * QKVD + (lc << 3),
                       &Ksd[buf][(it * 256 + wv * 64) * 8]);
        }
    };
    // DMA one 64-key V^T tile (16 KB) into Vtsd[buf] with XOR-chunk swizzle.
    auto dma_v = [&](int j0, int buf) {
        #pragma unroll
        for (int it = 0; it < 4; ++it) {
            const int P   = it * 256 + tid;          // physical chunk 0..1023
            const int row = P >> 3;                  // d 0..127
            const int lc  = (P & 7) ^ (row & 7);     // logical chunk (key/8)
            async_cp16(vbase + (size_t)row * T_ + j0 + (lc << 3),
                       &Vtsd[buf][(it * 256 + wv * 64) * 8]);
        }
    };

    #pragma unroll
    for (int qt = 0; qt < 2; ++qt) {
        const int i0 = ((qt == 0) ? (31 - nx) : nx) << 6;   // heavy tile first

        // Q fragments (B-operand of S^T = K*Q^T): lane's query = i0 + wv*16 + n16
        const int qrow = i0 + wv * 16 + n16;
        const u16* qp = qkv + (size_t)(b * T_ + qrow) * QKVD + h * DHD;
        short8 qf[4];
        #pragma unroll
        for (int kk = 0; kk < 4; ++kk)
            qf[kk] = *reinterpret_cast<const short8*>(qp + kk * 32 + quad * 8);

        floatx4 oacc[8];
        #pragma unroll
        for (int i = 0; i < 8; ++i) oacc[i] = (floatx4)0.0f;
        float m_cur = -INFINITY, l_cur = 0.0f;

        __syncthreads();             // all waves done reading buffers (prev qt)
        dma_k(0, 0);
        dma_v(0, 0);

        for (int j0 = 0; j0 <= i0; j0 += 64) {
            const int buf = (j0 >> 6) & 1;
            __syncthreads();         // drains this tile's DMA (vmcnt) + barrier
            if (j0 + 64 <= i0) {     // DMA next tile; lands by the NEXT barrier
                dma_k(j0 + 64, buf ^ 1);
                dma_v(j0 + 64, buf ^ 1);
            }
            const u16* kb = Ksd[buf];
            const u16* vb = Vtsd[buf];

            // ---- S^T = K * Q^T : st[t] covers keys [j0+t*16, j0+t*16+16)
            floatx4 st[4];
            #pragma unroll
            for (int t = 0; t < 4; ++t) st[t] = (floatx4)0.0f;
            #pragma unroll
            for (int t = 0; t < 4; ++t) {
                #pragma unroll
                for (int kk = 0; kk < 4; ++kk) {
                    short8 a = *reinterpret_cast<const short8*>(
                        &kb[(t * 16 + n16) * 128 + (((kk * 4 + quad) ^ n16) << 3)]);
                    st[t] = __builtin_amdgcn_mfma_f32_16x16x32_bf16(a, qf[kk], st[t], 0, 0, 0);
                }
            }

            // ---- causal mask + per-lane online softmax (lane's query = qrow)
            const bool diag = (j0 + 63 > i0 + wv * 16);
            float mloc = m_cur;
            #pragma unroll
            for (int t = 0; t < 4; ++t) {
                #pragma unroll
                for (int r = 0; r < 4; ++r) {
                    float s = st[t][r];
                    if (diag) {
                        const int key = j0 + t * 16 + quad * 4 + r;
                        if (key > qrow) s = -INFINITY;
                    }
                    st[t][r] = s;
                    mloc = fmaxf(mloc, s);
                }
            }
            mloc = fmaxf(mloc, __shfl_xor(mloc, 16));
            mloc = fmaxf(mloc, __shfl_xor(mloc, 32));
            const float alpha = exp2f((m_cur - mloc) * C1);
            m_cur = mloc;

            float lsum = 0.0f;
            #pragma unroll
            for (int t = 0; t < 4; ++t) {
                float p0 = exp2f((st[t][0] - mloc) * C1);
                float p1 = exp2f((st[t][1] - mloc) * C1);
                float p2 = exp2f((st[t][2] - mloc) * C1);
                float p3 = exp2f((st[t][3] - mloc) * C1);
                lsum += (p0 + p1) + (p2 + p3);
                uint2 pk;
                pk.x = (u32)f2bf(p0) | ((u32)f2bf(p1) << 16);
                pk.y = (u32)f2bf(p2) | ((u32)f2bf(p3) << 16);
                *reinterpret_cast<uint2*>(&plw[n16 * 72 + t * 16 + quad * 4]) = pk;
            }
            lsum += __shfl_xor(lsum, 16);
            lsum += __shfl_xor(lsum, 32);
            l_cur = l_cur * alpha + lsum;

            #pragma unroll
            for (int dt = 0; dt < 8; ++dt) {
                oacc[dt][0] *= alpha; oacc[dt][1] *= alpha;
                oacc[dt][2] *= alpha; oacc[dt][3] *= alpha;
            }

            // ---- O^T += V^T * P^T  (wave-private Pl; same-wave LDS in-order)
            #pragma unroll
            for (int kt = 0; kt < 2; ++kt) {
                short8 pfrag = *reinterpret_cast<const short8*>(&plw[n16 * 72 + kt * 32 + quad * 8]);
                #pragma unroll
                for (int dt = 0; dt < 8; ++dt) {
                    short8 vfrag = *reinterpret_cast<const short8*>(
                        &vb[(dt * 16 + n16) * 64 + (((kt * 4 + quad) ^ (n16 & 7)) << 3)]);
                    oacc[dt] = __builtin_amdgcn_mfma_f32_16x16x32_bf16(vfrag, pfrag, oacc[dt], 0, 0, 0);
                }
            }
        }

        // ---- epilogue: O^T[d][q] regs -> y[qrow][h*128 + d], d = dt*16+quad*4+r
        const float linv = 1.0f / l_cur;
        u16* yp = y + (size_t)(b * T_ + qrow) * CEMB + h * DHD + quad * 4;
        #pragma unroll
        for (int dt = 0; dt < 8; ++dt) {
            u32 w0 = (u32)f2bf(oacc[dt][0] * linv) | ((u32)f2bf(oacc[dt][1] * linv) << 16);
            u32 w1 = (u32)f2bf(oacc[dt][2] * linv) | ((u32)f2bf(oacc[dt][3] * linv) << 16);
            *reinterpret_cast<u32*>(yp + dt * 16)     = w0;
            *reinterpret_cast<u32*>(yp + dt * 16 + 2) = w1;
        }
    }
}

// ---------------------------------------------------------------------------
extern "C" void kernel_launch(void* const* d_in, const int* in_sizes, int n_in,
                              void* d_out, int out_size, void* d_ws, size_t ws_size,
                              hipStream_t stream) {
    const size_t NX   = (size_t)B_ * T_ * CEMB;     // 8,388,608
    const size_t NWQ  = (size_t)CEMB * QKVD;        // 6,291,456
    const size_t NWO  = (size_t)CEMB * CEMB;        // 4,194,304
    const size_t NQKV = (size_t)B_ * T_ * QKVD;     // 12,582,912
    const size_t NY   = NX;

    u16* qkv = (u16*)d_ws;
    u16* y   = qkv + NQKV;
    u16* xb  = y + NY;
    u16* wqT = xb + NX;
    u16* woT = wqT + NWQ;
    u16* vtb = xb;   // alias: xb dead after GEMM1; Vt needs 2.1M u16 <= 8.4M

    // --- input conversion (f32 -> bf16), weights transposed for BT GEMM
    convert_kernel<<<(int)(NX / 8 + 255) / 256, 256, 0, stream>>>((const float*)d_in[0], xb, (int)(NX / 8));
    transpose_f32_bf16<<<dim3(QKVD / 32, CEMB / 32), 256, 0, stream>>>((const float*)d_in[1], wqT, CEMB, QKVD);
    transpose_f32_bf16<<<dim3(CEMB / 32, CEMB / 32), 256, 0, stream>>>((const float*)d_in[2], woT, CEMB, CEMB);

    // --- GEMM1: qkv = x @ w_qkv (bf16 out)
    gemm_mfma_kernel<false><<<dim3(QKVD / 128, (B_ * T_) / 128), 256, 0, stream>>>(
        xb, wqT, qkv, B_ * T_, QKVD, CEMB);

    // --- RoPE constants (host, double precision, mirrors numpy)
    const double two_pi = 6.283185307179586476925286766559;
    double corr4 = 128.0 * log(4096.0 / (4.0 * two_pi)) / (2.0 * log(1.0e6));
    double corr1 = 128.0 * log(4096.0 / (1.0 * two_pi)) / (2.0 * log(1.0e6));
    double lowd  = floor(corr4); if (lowd < 0.0) lowd = 0.0;
    double highd = ceil(corr1);  if (highd > 127.0) highd = 127.0;
    if (lowd == highd) highd += 0.001;
    float attn_factor = (float)(0.1 * log(64.0) + 1.0);

    const int rope_total = B_ * T_ * (NH + NKV) * (DHD / 2);
    rope_kernel<<<(rope_total + 255) / 256, 256, 0, stream>>>(
        qkv, attn_factor, (float)lowd, (float)highd);

    // --- V^T buffer (overwrites xb, which is no longer needed)
    vt_build_kernel<<<dim3(T_ / 32, DHD / 32, B_ * NKV), 256, 0, stream>>>(qkv, vtb);

    // --- flash attention -> y (bf16); balanced pairing grid (16, 32)
    attn_mfma_kernel<<<dim3(T_ / 128, B_ * NH), 256, 0, stream>>>(qkv, vtb, y);

    // --- GEMM2: out = y @ w_o (f32 out)
    gemm_mfma_kernel<true><<<dim3(CEMB / 128, (B_ * T_) / 128), 256, 0, stream>>>(
        y, woT, d_out, B_ * T_, CEMB, CEMB);
}